// Round 1
// baseline (346.900 us; speedup 1.0000x reference)
//
#include <hip/hip_runtime.h>
#include <hip/hip_bf16.h>
#include <math.h>

typedef __bf16 bf16;
typedef __bf16 v8bf __attribute__((ext_vector_type(8)));
typedef float v4f __attribute__((ext_vector_type(4)));

#define N_TOK 2048
#define DIM 1024
#define NH 16
#define FFN_DIM 2816

// ---------- transpose + f32->bf16 convert: Wt[n][k] = (bf16)W[k][n] ----------
__global__ __launch_bounds__(256) void transpose_cvt_kernel(
    const float* __restrict__ W, bf16* __restrict__ Wt, int K, int Nc)
{
    __shared__ float tile[32][33];
    int tx = threadIdx.x, ty = threadIdx.y;
    int nb = blockIdx.x * 32, kb = blockIdx.y * 32;
#pragma unroll
    for (int r = 0; r < 4; ++r) {
        int k = kb + ty + r * 8;
        tile[ty + r * 8][tx] = W[(size_t)k * Nc + nb + tx];
    }
    __syncthreads();
#pragma unroll
    for (int r = 0; r < 4; ++r) {
        int n = nb + ty + r * 8;
        Wt[(size_t)n * K + kb + tx] = (bf16)tile[tx][ty + r * 8];
    }
}

// ---------- RMSNorm (f32 in -> bf16 out), one row per block ----------
__global__ __launch_bounds__(256) void rmsnorm_kernel(
    const float* __restrict__ x, const float* __restrict__ scale, bf16* __restrict__ out)
{
    int row = blockIdx.x, tid = threadIdx.x;
    float4 v = ((const float4*)(x + (size_t)row * DIM))[tid];
    float ss = v.x * v.x + v.y * v.y + v.z * v.z + v.w * v.w;
#pragma unroll
    for (int off = 32; off > 0; off >>= 1) ss += __shfl_down(ss, off);
    __shared__ float ps[4];
    if ((tid & 63) == 0) ps[tid >> 6] = ss;
    __syncthreads();
    float tot = ps[0] + ps[1] + ps[2] + ps[3];
    float inv = rsqrtf(tot * (1.0f / DIM) + 1e-6f);
    float4 s = ((const float4*)scale)[tid];
    union { bf16 b[4]; uint2 u; } p;
    p.b[0] = (bf16)(v.x * inv * s.x);
    p.b[1] = (bf16)(v.y * inv * s.y);
    p.b[2] = (bf16)(v.z * inv * s.z);
    p.b[3] = (bf16)(v.w * inv * s.w);
    ((uint2*)(out + (size_t)row * DIM))[tid] = p.u;
}

// ---------- gathered-offset attention: 1 wave per (t, h) ----------
__global__ __launch_bounds__(64) void attn_kernel(
    const bf16* __restrict__ qkv, const int* __restrict__ offs,
    const float* __restrict__ pos_bias, bf16* __restrict__ attb, int O)
{
    int t = blockIdx.x, h = blockIdx.y, lane = threadIdx.x;
    __shared__ float qs[64];
    __shared__ float al[64];
    __shared__ int so[64];
    const bf16* qrow = qkv + (size_t)t * (3 * DIM) + h * 64;
    qs[lane] = (float)qrow[lane] * 0.125f;  // HD=64 -> scale 1/8
    so[lane] = (lane < O) ? offs[lane] : 0;
    __syncthreads();
    float score = -INFINITY;
    if (lane < O) {
        int src = t - so[lane];
        if (src >= 0) {
            const v8bf* k8 = (const v8bf*)(qkv + (size_t)src * (3 * DIM) + DIM + h * 64);
            float s = 0.f;
#pragma unroll
            for (int dd = 0; dd < 8; ++dd) {
                v8bf kv = k8[dd];
#pragma unroll
                for (int e = 0; e < 8; ++e) s += qs[dd * 8 + e] * (float)kv[e];
            }
            score = s + pos_bias[lane * NH + h];
        }
    }
    al[lane] = score;
    __syncthreads();
    float m = -INFINITY;
    for (int o = 0; o < O; ++o) m = fmaxf(m, al[o]);
    float sum = 0.f;
    for (int o = 0; o < O; ++o) sum += __expf(al[o] - m);
    __syncthreads();
    al[lane] = (lane < O) ? __expf(score - m) / sum : 0.f;
    __syncthreads();
    float acc = 0.f;
    for (int o = 0; o < O; ++o) {
        float a = al[o];
        if (a > 0.f) {
            int src = t - so[o]; if (src < 0) src = 0;
            acc += a * (float)qkv[(size_t)src * (3 * DIM) + 2 * DIM + h * 64 + lane];
        }
    }
    attb[(size_t)t * DIM + h * 64 + lane] = (bf16)acc;
}

// ---------- bf16 MFMA GEMM: C[M,N] = A[M,K] * Bt[N,K]^T, 128x128 tile ----------
// EPI: 0 = store bf16; 1 = store f32; 2 = gate (outb = eb * sigmoid(acc+bias[col]));
//      3 = residual f32 (outf = e1 + acc); 4 = ffn-up (outb = silu(e1) * acc)
template<int EPI>
__global__ __launch_bounds__(256) void gemm_kernel(
    const bf16* __restrict__ A, const bf16* __restrict__ Bt,
    int M, int N, int K,
    float* __restrict__ outf, bf16* __restrict__ outb,
    const float* __restrict__ e1, const bf16* __restrict__ eb,
    const float* __restrict__ bias)
{
    __shared__ bf16 As[128][40];
    __shared__ bf16 Bs[128][40];
    const int tid = threadIdx.x;
    const int m0 = blockIdx.y * 128, n0 = blockIdx.x * 128;
    const int lane = tid & 63, wave = tid >> 6;
    const int wm = (wave >> 1) * 64, wn = (wave & 1) * 64;
    const int lrow = lane & 15, lk = (lane >> 4) * 8;
    // staging map: 512 chunks of 8 bf16; 4 chunks per row
    const int e0 = tid, ar0 = e0 >> 2, ak0 = (e0 & 3) * 8;
    const int e1i = tid + 256, ar1 = e1i >> 2, ak1 = (e1i & 3) * 8;

    v4f acc[4][4] = {};
    for (int k0 = 0; k0 < K; k0 += 32) {
        __syncthreads();
        *(uint4*)&As[ar0][ak0] = *(const uint4*)&A[(size_t)(m0 + ar0) * K + k0 + ak0];
        *(uint4*)&As[ar1][ak1] = *(const uint4*)&A[(size_t)(m0 + ar1) * K + k0 + ak1];
        *(uint4*)&Bs[ar0][ak0] = *(const uint4*)&Bt[(size_t)(n0 + ar0) * K + k0 + ak0];
        *(uint4*)&Bs[ar1][ak1] = *(const uint4*)&Bt[(size_t)(n0 + ar1) * K + k0 + ak1];
        __syncthreads();
        v8bf af[4], bfr[4];
#pragma unroll
        for (int i = 0; i < 4; ++i) af[i] = *(v8bf*)&As[wm + i * 16 + lrow][lk];
#pragma unroll
        for (int j = 0; j < 4; ++j) bfr[j] = *(v8bf*)&Bs[wn + j * 16 + lrow][lk];
#pragma unroll
        for (int i = 0; i < 4; ++i)
#pragma unroll
            for (int j = 0; j < 4; ++j)
                acc[i][j] = __builtin_amdgcn_mfma_f32_16x16x32_bf16(af[i], bfr[j], acc[i][j], 0, 0, 0);
    }

#pragma unroll
    for (int i = 0; i < 4; ++i)
#pragma unroll
        for (int j = 0; j < 4; ++j)
#pragma unroll
            for (int r = 0; r < 4; ++r) {
                int row = m0 + wm + i * 16 + ((lane >> 4) << 2) + r;
                int col = n0 + wn + j * 16 + (lane & 15);
                size_t idx = (size_t)row * N + col;
                float v = acc[i][j][r];
                if constexpr (EPI == 0) {
                    outb[idx] = (bf16)v;
                } else if constexpr (EPI == 1) {
                    outf[idx] = v;
                } else if constexpr (EPI == 2) {
                    float g = 1.0f / (1.0f + __expf(-(v + bias[col])));
                    outb[idx] = (bf16)((float)eb[idx] * g);
                } else if constexpr (EPI == 3) {
                    outf[idx] = e1[idx] + v;
                } else {
                    float gg = e1[idx];
                    float sil = gg / (1.0f + __expf(-gg));
                    outb[idx] = (bf16)(sil * v);
                }
            }
}

extern "C" void kernel_launch(void* const* d_in, const int* in_sizes, int n_in,
                              void* d_out, int out_size, void* d_ws, size_t ws_size,
                              hipStream_t stream)
{
    const float* x        = (const float*)d_in[0];
    const float* n1s      = (const float*)d_in[1];
    const float* n2s      = (const float*)d_in[2];
    const float* w_qkv    = (const float*)d_in[3];
    const float* w_out    = (const float*)d_in[4];
    const float* w_gate   = (const float*)d_in[5];
    const float* b_gate   = (const float*)d_in[6];
    const float* pos_bias = (const float*)d_in[7];
    const float* w_ffng   = (const float*)d_in[8];
    const float* w_ffnu   = (const float*)d_in[9];
    const float* w_ffnd   = (const float*)d_in[10];
    const int* offsets    = (const int*)d_in[11];
    const int O = in_sizes[11];
    float* out = (float*)d_out;

    char* ws = (char*)d_ws;
    size_t cur = 0;
    auto alloc = [&](size_t bytes) -> void* {
        void* p = ws + cur;
        cur += (bytes + 255) & ~(size_t)255;
        return p;
    };
    bf16*  xnb    = (bf16*)alloc((size_t)N_TOK * DIM * 2);
    bf16*  qkvb   = (bf16*)alloc((size_t)N_TOK * 3 * DIM * 2);
    bf16*  attb   = (bf16*)alloc((size_t)N_TOK * DIM * 2);
    bf16*  attgb  = (bf16*)alloc((size_t)N_TOK * DIM * 2);
    float* x1     = (float*)alloc((size_t)N_TOK * DIM * 4);
    bf16*  xn2b   = (bf16*)alloc((size_t)N_TOK * DIM * 2);
    float* hg     = (float*)alloc((size_t)N_TOK * FFN_DIM * 4);
    bf16*  hb     = (bf16*)alloc((size_t)N_TOK * FFN_DIM * 2);
    bf16*  wqkvT  = (bf16*)alloc((size_t)3 * DIM * DIM * 2);
    bf16*  woutT  = (bf16*)alloc((size_t)DIM * DIM * 2);
    bf16*  wgateT = (bf16*)alloc((size_t)DIM * DIM * 2);
    bf16*  wffngT = (bf16*)alloc((size_t)DIM * FFN_DIM * 2);
    bf16*  wffnuT = (bf16*)alloc((size_t)DIM * FFN_DIM * 2);
    bf16*  wffndT = (bf16*)alloc((size_t)FFN_DIM * DIM * 2);

    dim3 tb(32, 8);
    transpose_cvt_kernel<<<dim3(3 * DIM / 32, DIM / 32), tb, 0, stream>>>(w_qkv, wqkvT, DIM, 3 * DIM);
    transpose_cvt_kernel<<<dim3(DIM / 32, DIM / 32), tb, 0, stream>>>(w_out, woutT, DIM, DIM);
    transpose_cvt_kernel<<<dim3(DIM / 32, DIM / 32), tb, 0, stream>>>(w_gate, wgateT, DIM, DIM);
    transpose_cvt_kernel<<<dim3(FFN_DIM / 32, DIM / 32), tb, 0, stream>>>(w_ffng, wffngT, DIM, FFN_DIM);
    transpose_cvt_kernel<<<dim3(FFN_DIM / 32, DIM / 32), tb, 0, stream>>>(w_ffnu, wffnuT, DIM, FFN_DIM);
    transpose_cvt_kernel<<<dim3(DIM / 32, FFN_DIM / 32), tb, 0, stream>>>(w_ffnd, wffndT, FFN_DIM, DIM);

    // norm1 -> xnb
    rmsnorm_kernel<<<N_TOK, 256, 0, stream>>>(x, n1s, xnb);
    // qkv = xn @ w_qkv  (bf16 out)
    gemm_kernel<0><<<dim3(3 * DIM / 128, N_TOK / 128), 256, 0, stream>>>(
        xnb, wqkvT, N_TOK, 3 * DIM, DIM, nullptr, qkvb, nullptr, nullptr, nullptr);
    // attention -> attb
    attn_kernel<<<dim3(N_TOK, NH), 64, 0, stream>>>(qkvb, offsets, pos_bias, attb, O);
    // attg = att * sigmoid(xn @ w_gate + b_gate)  (bf16 out)
    gemm_kernel<2><<<dim3(DIM / 128, N_TOK / 128), 256, 0, stream>>>(
        xnb, wgateT, N_TOK, DIM, DIM, nullptr, attgb, nullptr, attb, b_gate);
    // x1 = x + attg @ w_out  (f32)
    gemm_kernel<3><<<dim3(DIM / 128, N_TOK / 128), 256, 0, stream>>>(
        attgb, woutT, N_TOK, DIM, DIM, x1, nullptr, x, nullptr, nullptr);
    // norm2 -> xn2b
    rmsnorm_kernel<<<N_TOK, 256, 0, stream>>>(x1, n2s, xn2b);
    // hg = xn2 @ w_ffn_gate (f32)
    gemm_kernel<1><<<dim3(FFN_DIM / 128, N_TOK / 128), 256, 0, stream>>>(
        xn2b, wffngT, N_TOK, FFN_DIM, DIM, hg, nullptr, nullptr, nullptr, nullptr);
    // hb = silu(hg) * (xn2 @ w_ffn_up)  (bf16)
    gemm_kernel<4><<<dim3(FFN_DIM / 128, N_TOK / 128), 256, 0, stream>>>(
        xn2b, wffnuT, N_TOK, FFN_DIM, DIM, nullptr, hb, hg, nullptr, nullptr);
    // out = x1 + hb @ w_ffn_down  (f32, final)
    gemm_kernel<3><<<dim3(DIM / 128, N_TOK / 128), 256, 0, stream>>>(
        hb, wffndT, N_TOK, DIM, FFN_DIM, out, nullptr, x1, nullptr, nullptr);
}

// Round 2
// 261.847 us; speedup vs baseline: 1.3248x; 1.3248x over previous
//
#include <hip/hip_runtime.h>
#include <hip/hip_bf16.h>
#include <math.h>

typedef __bf16 bf16;
typedef __bf16 v8bf __attribute__((ext_vector_type(8)));
typedef __bf16 v4bf __attribute__((ext_vector_type(4)));
typedef float v4f __attribute__((ext_vector_type(4)));

#define N_TOK 2048
#define DIM 1024
#define NH 16
#define FFN_DIM 2816

#define GLL(g, l) __builtin_amdgcn_global_load_lds(                         \
    (const __attribute__((address_space(1))) uint32_t*)(g),                 \
    (__attribute__((address_space(3))) uint32_t*)(l), 16, 0, 0)

// ---------- transpose + f32->bf16 convert: Wt[n][k] = (bf16)W[k][n] ----------
__global__ __launch_bounds__(256) void transpose_cvt_kernel(
    const float* __restrict__ W, bf16* __restrict__ Wt, int K, int Nc)
{
    __shared__ float tile[32][33];
    int tx = threadIdx.x, ty = threadIdx.y;
    int nb = blockIdx.x * 32, kb = blockIdx.y * 32;
#pragma unroll
    for (int r = 0; r < 4; ++r) {
        int k = kb + ty + r * 8;
        tile[ty + r * 8][tx] = W[(size_t)k * Nc + nb + tx];
    }
    __syncthreads();
#pragma unroll
    for (int r = 0; r < 4; ++r) {
        int n = nb + ty + r * 8;
        Wt[(size_t)n * K + kb + tx] = (bf16)tile[tx][ty + r * 8];
    }
}

// ---------- RMSNorm (f32 in -> bf16 out), one row per block ----------
__global__ __launch_bounds__(256) void rmsnorm_kernel(
    const float* __restrict__ x, const float* __restrict__ scale, bf16* __restrict__ out)
{
    int row = blockIdx.x, tid = threadIdx.x;
    float4 v = ((const float4*)(x + (size_t)row * DIM))[tid];
    float ss = v.x * v.x + v.y * v.y + v.z * v.z + v.w * v.w;
#pragma unroll
    for (int off = 32; off > 0; off >>= 1) ss += __shfl_down(ss, off);
    __shared__ float ps[4];
    if ((tid & 63) == 0) ps[tid >> 6] = ss;
    __syncthreads();
    float tot = ps[0] + ps[1] + ps[2] + ps[3];
    float inv = rsqrtf(tot * (1.0f / DIM) + 1e-6f);
    float4 s = ((const float4*)scale)[tid];
    union { bf16 b[4]; uint2 u; } p;
    p.b[0] = (bf16)(v.x * inv * s.x);
    p.b[1] = (bf16)(v.y * inv * s.y);
    p.b[2] = (bf16)(v.z * inv * s.z);
    p.b[3] = (bf16)(v.w * inv * s.w);
    ((uint2*)(out + (size_t)row * DIM))[tid] = p.u;
}

// ---------- gathered-offset attention: 1 block per token, all 16 heads ----------
// thread tid: head h = tid>>4, sub-lane j16 = tid&15, dims [tid*4, tid*4+4)
__global__ __launch_bounds__(256) void attn_kernel(
    const bf16* __restrict__ qkv, const int* __restrict__ offs,
    const float* __restrict__ pos_bias, bf16* __restrict__ attb, int O)
{
    const int t = blockIdx.x, tid = threadIdx.x;
    const int h = tid >> 4, j16 = tid & 15;
    __shared__ float sS[64][16];   // [o][h] scores -> unnormalized probs
    __shared__ int so[64];
    if (tid < 64) so[tid] = (tid < 64 && tid < O) ? offs[tid] : 0;
    __syncthreads();

    v4bf qv = *(const v4bf*)(qkv + (size_t)t * (3 * DIM) + tid * 4);
    float q0 = (float)qv[0] * 0.125f, q1 = (float)qv[1] * 0.125f;
    float q2 = (float)qv[2] * 0.125f, q3 = (float)qv[3] * 0.125f;

    // phase 1: scores (uniform branch per o; 16-lane reduce per head)
    for (int o = 0; o < O; ++o) {
        int src = t - so[o];
        float s = -INFINITY;
        if (src >= 0) {
            v4bf kv = *(const v4bf*)(qkv + (size_t)src * (3 * DIM) + DIM + tid * 4);
            float p = q0 * (float)kv[0] + q1 * (float)kv[1]
                    + q2 * (float)kv[2] + q3 * (float)kv[3];
            p += __shfl_xor(p, 1);
            p += __shfl_xor(p, 2);
            p += __shfl_xor(p, 4);
            p += __shfl_xor(p, 8);
            s = p + pos_bias[o * NH + h];
        }
        if (j16 == 0) sS[o][h] = s;
    }

    // phase 2: per-head softmax stats (same wave owns the head's data)
    float mx = -INFINITY;
    for (int o = j16; o < O; o += 16) mx = fmaxf(mx, sS[o][h]);
    mx = fmaxf(mx, __shfl_xor(mx, 1));
    mx = fmaxf(mx, __shfl_xor(mx, 2));
    mx = fmaxf(mx, __shfl_xor(mx, 4));
    mx = fmaxf(mx, __shfl_xor(mx, 8));
    float sum = 0.f;
    for (int o = j16; o < O; o += 16) {
        float e = __expf(sS[o][h] - mx);
        sS[o][h] = e;
        sum += e;
    }
    sum += __shfl_xor(sum, 1);
    sum += __shfl_xor(sum, 2);
    sum += __shfl_xor(sum, 4);
    sum += __shfl_xor(sum, 8);
    float inv = 1.0f / sum;

    // phase 3: PV accumulate (normalize at the end)
    float a0 = 0.f, a1 = 0.f, a2 = 0.f, a3 = 0.f;
    for (int o = 0; o < O; ++o) {
        int src = t - so[o];
        if (src >= 0) {
            float a = sS[o][h];
            v4bf vv = *(const v4bf*)(qkv + (size_t)src * (3 * DIM) + 2 * DIM + tid * 4);
            a0 += a * (float)vv[0];
            a1 += a * (float)vv[1];
            a2 += a * (float)vv[2];
            a3 += a * (float)vv[3];
        }
    }
    v4bf ov;
    ov[0] = (bf16)(a0 * inv); ov[1] = (bf16)(a1 * inv);
    ov[2] = (bf16)(a2 * inv); ov[3] = (bf16)(a3 * inv);
    *(v4bf*)(attb + (size_t)t * DIM + tid * 4) = ov;
}

// ---------- bf16 MFMA GEMM, m97 structure: 128xBN tile, BK=32, global_load_lds ----------
// EPI: 0 = store bf16; 1 = store f32; 2 = gate (outb = eb * sigmoid(acc+bias[col]));
//      3 = residual f32 (outf = e1 + acc); 4 = ffn-up (outb = silu(e1) * acc)
template<int BN, int EPI>
__global__ __launch_bounds__(256) void gemm_kernel(
    const bf16* __restrict__ A, const bf16* __restrict__ Bt,
    int M, int N, int K,
    float* __restrict__ outf, bf16* __restrict__ outb,
    const float* __restrict__ e1, const bf16* __restrict__ eb,
    const float* __restrict__ bias)
{
    constexpr int WN = BN / 2;        // per-wave N extent
    constexpr int NJ = WN / 16;       // B fragments per wave
    __shared__ bf16 As[128 * 32];
    __shared__ bf16 Bs[BN * 32];
    const int tid = threadIdx.x;
    const int m0 = blockIdx.y * 128, n0 = blockIdx.x * BN;
    const int lane = tid & 63, wave = tid >> 6;
    const int wm = (wave >> 1) * 64, wn = (wave & 1) * WN;
    const int lrow = lane & 15, lk = (lane >> 4) * 8;

    // staging: chunk c covers LDS bytes [c*16, c*16+16); row = c/4, 16B-col = c%4
    const int srow = tid >> 2, scol = (tid & 3) * 8;
    const bf16* gA0 = A + (size_t)(m0 + srow) * K + scol;
    const bf16* gA1 = A + (size_t)(m0 + 64 + srow) * K + scol;
    const bf16* gB0 = Bt + (size_t)(n0 + srow) * K + scol;
    const bf16* gB1 = Bt + (size_t)(n0 + 64 + srow) * K + scol;
    bf16* lA0 = &As[srow * 32 + scol];
    bf16* lA1 = &As[(64 + srow) * 32 + scol];
    bf16* lB0 = &Bs[srow * 32 + scol];
    bf16* lB1 = &Bs[(64 + srow) * 32 + scol];

    v4f acc[4][NJ] = {};
    for (int k0 = 0; k0 < K; k0 += 32) {
        GLL(gA0 + k0, lA0);
        GLL(gA1 + k0, lA1);
        GLL(gB0 + k0, lB0);
        if constexpr (BN == 128) GLL(gB1 + k0, lB1);
        asm volatile("s_waitcnt vmcnt(0)" ::: "memory");
        __syncthreads();
        v8bf af[4], bfr[NJ];
#pragma unroll
        for (int i = 0; i < 4; ++i) af[i] = *(v8bf*)&As[(wm + i * 16 + lrow) * 32 + lk];
#pragma unroll
        for (int j = 0; j < NJ; ++j) bfr[j] = *(v8bf*)&Bs[(wn + j * 16 + lrow) * 32 + lk];
#pragma unroll
        for (int i = 0; i < 4; ++i)
#pragma unroll
            for (int j = 0; j < NJ; ++j)
                acc[i][j] = __builtin_amdgcn_mfma_f32_16x16x32_bf16(af[i], bfr[j], acc[i][j], 0, 0, 0);
        __syncthreads();
    }

#pragma unroll
    for (int i = 0; i < 4; ++i)
#pragma unroll
        for (int j = 0; j < NJ; ++j)
#pragma unroll
            for (int r = 0; r < 4; ++r) {
                int row = m0 + wm + i * 16 + ((lane >> 4) << 2) + r;
                int col = n0 + wn + j * 16 + (lane & 15);
                size_t idx = (size_t)row * N + col;
                float v = acc[i][j][r];
                if constexpr (EPI == 0) {
                    outb[idx] = (bf16)v;
                } else if constexpr (EPI == 1) {
                    outf[idx] = v;
                } else if constexpr (EPI == 2) {
                    float g = 1.0f / (1.0f + __expf(-(v + bias[col])));
                    outb[idx] = (bf16)((float)eb[idx] * g);
                } else if constexpr (EPI == 3) {
                    outf[idx] = e1[idx] + v;
                } else {
                    float gg = e1[idx];
                    float sil = gg / (1.0f + __expf(-gg));
                    outb[idx] = (bf16)(sil * v);
                }
            }
}

extern "C" void kernel_launch(void* const* d_in, const int* in_sizes, int n_in,
                              void* d_out, int out_size, void* d_ws, size_t ws_size,
                              hipStream_t stream)
{
    const float* x        = (const float*)d_in[0];
    const float* n1s      = (const float*)d_in[1];
    const float* n2s      = (const float*)d_in[2];
    const float* w_qkv    = (const float*)d_in[3];
    const float* w_out    = (const float*)d_in[4];
    const float* w_gate   = (const float*)d_in[5];
    const float* b_gate   = (const float*)d_in[6];
    const float* pos_bias = (const float*)d_in[7];
    const float* w_ffng   = (const float*)d_in[8];
    const float* w_ffnu   = (const float*)d_in[9];
    const float* w_ffnd   = (const float*)d_in[10];
    const int* offsets    = (const int*)d_in[11];
    const int O = in_sizes[11];
    float* out = (float*)d_out;

    char* ws = (char*)d_ws;
    size_t cur = 0;
    auto alloc = [&](size_t bytes) -> void* {
        void* p = ws + cur;
        cur += (bytes + 255) & ~(size_t)255;
        return p;
    };
    bf16*  xnb    = (bf16*)alloc((size_t)N_TOK * DIM * 2);
    bf16*  qkvb   = (bf16*)alloc((size_t)N_TOK * 3 * DIM * 2);
    bf16*  attb   = (bf16*)alloc((size_t)N_TOK * DIM * 2);
    bf16*  attgb  = (bf16*)alloc((size_t)N_TOK * DIM * 2);
    float* x1     = (float*)alloc((size_t)N_TOK * DIM * 4);
    bf16*  xn2b   = (bf16*)alloc((size_t)N_TOK * DIM * 2);
    float* hg     = (float*)alloc((size_t)N_TOK * FFN_DIM * 4);
    bf16*  hb     = (bf16*)alloc((size_t)N_TOK * FFN_DIM * 2);
    bf16*  wqkvT  = (bf16*)alloc((size_t)3 * DIM * DIM * 2);
    bf16*  woutT  = (bf16*)alloc((size_t)DIM * DIM * 2);
    bf16*  wgateT = (bf16*)alloc((size_t)DIM * DIM * 2);
    bf16*  wffngT = (bf16*)alloc((size_t)DIM * FFN_DIM * 2);
    bf16*  wffnuT = (bf16*)alloc((size_t)DIM * FFN_DIM * 2);
    bf16*  wffndT = (bf16*)alloc((size_t)FFN_DIM * DIM * 2);

    dim3 tb(32, 8);
    transpose_cvt_kernel<<<dim3(3 * DIM / 32, DIM / 32), tb, 0, stream>>>(w_qkv, wqkvT, DIM, 3 * DIM);
    transpose_cvt_kernel<<<dim3(DIM / 32, DIM / 32), tb, 0, stream>>>(w_out, woutT, DIM, DIM);
    transpose_cvt_kernel<<<dim3(DIM / 32, DIM / 32), tb, 0, stream>>>(w_gate, wgateT, DIM, DIM);
    transpose_cvt_kernel<<<dim3(FFN_DIM / 32, DIM / 32), tb, 0, stream>>>(w_ffng, wffngT, DIM, FFN_DIM);
    transpose_cvt_kernel<<<dim3(FFN_DIM / 32, DIM / 32), tb, 0, stream>>>(w_ffnu, wffnuT, DIM, FFN_DIM);
    transpose_cvt_kernel<<<dim3(DIM / 32, FFN_DIM / 32), tb, 0, stream>>>(w_ffnd, wffndT, FFN_DIM, DIM);

    rmsnorm_kernel<<<N_TOK, 256, 0, stream>>>(x, n1s, xnb);
    gemm_kernel<128, 0><<<dim3(3 * DIM / 128, N_TOK / 128), 256, 0, stream>>>(
        xnb, wqkvT, N_TOK, 3 * DIM, DIM, nullptr, qkvb, nullptr, nullptr, nullptr);
    attn_kernel<<<dim3(N_TOK), 256, 0, stream>>>(qkvb, offsets, pos_bias, attb, O);
    gemm_kernel<64, 2><<<dim3(DIM / 64, N_TOK / 128), 256, 0, stream>>>(
        xnb, wgateT, N_TOK, DIM, DIM, nullptr, attgb, nullptr, attb, b_gate);
    gemm_kernel<64, 3><<<dim3(DIM / 64, N_TOK / 128), 256, 0, stream>>>(
        attgb, woutT, N_TOK, DIM, DIM, x1, nullptr, x, nullptr, nullptr);
    rmsnorm_kernel<<<N_TOK, 256, 0, stream>>>(x1, n2s, xn2b);
    gemm_kernel<128, 1><<<dim3(FFN_DIM / 128, N_TOK / 128), 256, 0, stream>>>(
        xn2b, wffngT, N_TOK, FFN_DIM, DIM, hg, nullptr, nullptr, nullptr, nullptr);
    gemm_kernel<128, 4><<<dim3(FFN_DIM / 128, N_TOK / 128), 256, 0, stream>>>(
        xn2b, wffnuT, N_TOK, FFN_DIM, DIM, nullptr, hb, hg, nullptr, nullptr);
    gemm_kernel<64, 3><<<dim3(DIM / 64, N_TOK / 128), 256, 0, stream>>>(
        hb, wffndT, N_TOK, DIM, FFN_DIM, out, nullptr, x1, nullptr, nullptr);
}

// Round 3
// 221.116 us; speedup vs baseline: 1.5689x; 1.1842x over previous
//
#include <hip/hip_runtime.h>
#include <hip/hip_bf16.h>
#include <math.h>

typedef __bf16 bf16;
typedef __bf16 v8bf __attribute__((ext_vector_type(8)));
typedef __bf16 v4bf __attribute__((ext_vector_type(4)));
typedef float v4f __attribute__((ext_vector_type(4)));

#define N_TOK 2048
#define DIM 1024
#define NH 16
#define FFN_DIM 2816

#define GLL(g, l) __builtin_amdgcn_global_load_lds(                         \
    (const __attribute__((address_space(1))) uint32_t*)(g),                 \
    (__attribute__((address_space(3))) uint32_t*)(l), 16, 0, 0)

// ---------- transpose + f32->bf16 convert: Wt[n][k] = (bf16)W[k][n] ----------
__global__ __launch_bounds__(256) void transpose_cvt_kernel(
    const float* __restrict__ W, bf16* __restrict__ Wt, int K, int Nc)
{
    __shared__ float tile[32][33];
    int tx = threadIdx.x, ty = threadIdx.y;
    int nb = blockIdx.x * 32, kb = blockIdx.y * 32;
#pragma unroll
    for (int r = 0; r < 4; ++r) {
        int k = kb + ty + r * 8;
        tile[ty + r * 8][tx] = W[(size_t)k * Nc + nb + tx];
    }
    __syncthreads();
#pragma unroll
    for (int r = 0; r < 4; ++r) {
        int n = nb + ty + r * 8;
        Wt[(size_t)n * K + kb + tx] = (bf16)tile[tx][ty + r * 8];
    }
}

// ---------- RMSNorm (f32 in -> bf16 out), one row per block ----------
__global__ __launch_bounds__(256) void rmsnorm_kernel(
    const float* __restrict__ x, const float* __restrict__ scale, bf16* __restrict__ out)
{
    int row = blockIdx.x, tid = threadIdx.x;
    float4 v = ((const float4*)(x + (size_t)row * DIM))[tid];
    float ss = v.x * v.x + v.y * v.y + v.z * v.z + v.w * v.w;
#pragma unroll
    for (int off = 32; off > 0; off >>= 1) ss += __shfl_down(ss, off);
    __shared__ float ps[4];
    if ((tid & 63) == 0) ps[tid >> 6] = ss;
    __syncthreads();
    float tot = ps[0] + ps[1] + ps[2] + ps[3];
    float inv = rsqrtf(tot * (1.0f / DIM) + 1e-6f);
    float4 s = ((const float4*)scale)[tid];
    union { bf16 b[4]; uint2 u; } p;
    p.b[0] = (bf16)(v.x * inv * s.x);
    p.b[1] = (bf16)(v.y * inv * s.y);
    p.b[2] = (bf16)(v.z * inv * s.z);
    p.b[3] = (bf16)(v.w * inv * s.w);
    ((uint2*)(out + (size_t)row * DIM))[tid] = p.u;
}

// ---------- gathered-offset attention + gate multiply ----------
// qkvg row layout: [q(0:1024) | k(1024:2048) | v(2048:3072) | gate(3072:4096)]
__global__ __launch_bounds__(256) void attn_kernel(
    const bf16* __restrict__ qkvg, const int* __restrict__ offs,
    const float* __restrict__ pos_bias, bf16* __restrict__ attgb, int O)
{
    const int t = blockIdx.x, tid = threadIdx.x;
    const int h = tid >> 4, j16 = tid & 15;
    const size_t RS = 4 * DIM;
    __shared__ float sS[64][16];
    __shared__ int so[64];
    if (tid < 64) so[tid] = (tid < O) ? offs[tid] : 0;
    __syncthreads();

    v4bf qv = *(const v4bf*)(qkvg + (size_t)t * RS + tid * 4);
    float q0 = (float)qv[0] * 0.125f, q1 = (float)qv[1] * 0.125f;
    float q2 = (float)qv[2] * 0.125f, q3 = (float)qv[3] * 0.125f;

    for (int o = 0; o < O; ++o) {
        int src = t - so[o];
        float s = -INFINITY;
        if (src >= 0) {
            v4bf kv = *(const v4bf*)(qkvg + (size_t)src * RS + DIM + tid * 4);
            float p = q0 * (float)kv[0] + q1 * (float)kv[1]
                    + q2 * (float)kv[2] + q3 * (float)kv[3];
            p += __shfl_xor(p, 1);
            p += __shfl_xor(p, 2);
            p += __shfl_xor(p, 4);
            p += __shfl_xor(p, 8);
            s = p + pos_bias[o * NH + h];
        }
        if (j16 == 0) sS[o][h] = s;
    }

    float mx = -INFINITY;
    for (int o = j16; o < O; o += 16) mx = fmaxf(mx, sS[o][h]);
    mx = fmaxf(mx, __shfl_xor(mx, 1));
    mx = fmaxf(mx, __shfl_xor(mx, 2));
    mx = fmaxf(mx, __shfl_xor(mx, 4));
    mx = fmaxf(mx, __shfl_xor(mx, 8));
    float sum = 0.f;
    for (int o = j16; o < O; o += 16) {
        float e = __expf(sS[o][h] - mx);
        sS[o][h] = e;
        sum += e;
    }
    sum += __shfl_xor(sum, 1);
    sum += __shfl_xor(sum, 2);
    sum += __shfl_xor(sum, 4);
    sum += __shfl_xor(sum, 8);
    float inv = 1.0f / sum;

    float a0 = 0.f, a1 = 0.f, a2 = 0.f, a3 = 0.f;
    for (int o = 0; o < O; ++o) {
        int src = t - so[o];
        if (src >= 0) {
            float a = sS[o][h];
            v4bf vv = *(const v4bf*)(qkvg + (size_t)src * RS + 2 * DIM + tid * 4);
            a0 += a * (float)vv[0];
            a1 += a * (float)vv[1];
            a2 += a * (float)vv[2];
            a3 += a * (float)vv[3];
        }
    }
    v4bf gv = *(const v4bf*)(qkvg + (size_t)t * RS + 3 * DIM + tid * 4);
    v4bf ov;
    ov[0] = (bf16)(a0 * inv * (float)gv[0]);
    ov[1] = (bf16)(a1 * inv * (float)gv[1]);
    ov[2] = (bf16)(a2 * inv * (float)gv[2]);
    ov[3] = (bf16)(a3 * inv * (float)gv[3]);
    *(v4bf*)(attgb + (size_t)t * DIM + tid * 4) = ov;
}

// ---------- bf16 MFMA GEMM: 128xBN tile, BK=32, 3-deep pipelined global_load_lds ----------
// swizzle: 16B chunk column c XOR'd with (row>>1)&3 (pre-swizzled global source,
// linear LDS dest; ds_read applies the same XOR)
// EPI: 1 = f32 store; 3 = residual f32 (outf = e1 + acc); 4 = ffn-up (silu(e1)*acc ->bf16);
//      5 = qkv+gate (col<3072: bf16 acc; col>=3072: bf16 sigmoid(acc+bias[col-3072]))
template<int BN, int EPI>
__global__ __launch_bounds__(256) void gemm_kernel(
    const bf16* __restrict__ A, const bf16* __restrict__ Bt,
    int M, int N, int K,
    float* __restrict__ outf, bf16* __restrict__ outb,
    const float* __restrict__ e1, const float* __restrict__ bias)
{
    constexpr int WN = BN / 2;
    constexpr int NJ = WN / 16;
    constexpr int NBUF = 3;
    __shared__ bf16 As[NBUF][128 * 32];
    __shared__ bf16 Bs[NBUF][BN * 32];
    const int tid = threadIdx.x;
    const int m0 = blockIdx.y * 128, n0 = blockIdx.x * BN;
    const int lane = tid & 63, wave = tid >> 6;
    const int wm = (wave >> 1) * 64, wn = (wave & 1) * WN;
    const int lrow = lane & 15;

    // staging: thread tid -> LDS chunk (srow, tid&3) (linear); global col pre-swizzled
    const int srow = tid >> 2;
    const int gcol = ((tid & 3) ^ ((srow >> 1) & 3)) * 8;
    const int lcol = (tid & 3) * 8;
    const bf16* gA0 = A + (size_t)(m0 + srow) * K + gcol;
    const bf16* gA1 = A + (size_t)(m0 + 64 + srow) * K + gcol;
    const bf16* gB0 = Bt + (size_t)(n0 + srow) * K + gcol;
    const bf16* gB1 = Bt + (size_t)(n0 + 64 + srow) * K + gcol;
    const int lA0o = srow * 32 + lcol;
    const int lA1o = (64 + srow) * 32 + lcol;
    const int lB0o = srow * 32 + lcol;
    const int lB1o = (64 + srow) * 32 + lcol;

    auto STAGE = [&](int b, int kt) {
        const int ko = kt * 32;
        GLL(gA0 + ko, &As[b][lA0o]);
        GLL(gA1 + ko, &As[b][lA1o]);
        GLL(gB0 + ko, &Bs[b][lB0o]);
        if constexpr (BN == 128) GLL(gB1 + ko, &Bs[b][lB1o]);
    };

    v4f acc[4][NJ] = {};
    auto COMPUTE = [&](int b) {
        v8bf af[4], bfr[NJ];
#pragma unroll
        for (int i = 0; i < 4; ++i) {
            int r = wm + i * 16 + lrow;
            af[i] = *(v8bf*)&As[b][r * 32 + (((lane >> 4) ^ ((r >> 1) & 3)) * 8)];
        }
#pragma unroll
        for (int j = 0; j < NJ; ++j) {
            int r = wn + j * 16 + lrow;
            bfr[j] = *(v8bf*)&Bs[b][r * 32 + (((lane >> 4) ^ ((r >> 1) & 3)) * 8)];
        }
        __builtin_amdgcn_s_setprio(1);
#pragma unroll
        for (int i = 0; i < 4; ++i)
#pragma unroll
            for (int j = 0; j < NJ; ++j)
                acc[i][j] = __builtin_amdgcn_mfma_f32_16x16x32_bf16(af[i], bfr[j], acc[i][j], 0, 0, 0);
        __builtin_amdgcn_s_setprio(0);
    };

    const int NT = K >> 5;
    STAGE(0, 0); STAGE(1, 1); STAGE(2, 2);
    for (int t = 0; t < NT - 2; ++t) {
        if constexpr (BN == 128) asm volatile("s_waitcnt vmcnt(8)" ::: "memory");
        else                     asm volatile("s_waitcnt vmcnt(6)" ::: "memory");
        __builtin_amdgcn_s_barrier();
        __builtin_amdgcn_sched_barrier(0);
        COMPUTE(t % 3);
        __builtin_amdgcn_sched_barrier(0);
        __builtin_amdgcn_s_barrier();
        if (t + 3 < NT) STAGE(t % 3, t + 3);
    }
    if constexpr (BN == 128) asm volatile("s_waitcnt vmcnt(4)" ::: "memory");
    else                     asm volatile("s_waitcnt vmcnt(3)" ::: "memory");
    __builtin_amdgcn_s_barrier();
    __builtin_amdgcn_sched_barrier(0);
    COMPUTE((NT - 2) % 3);
    asm volatile("s_waitcnt vmcnt(0)" ::: "memory");
    __builtin_amdgcn_s_barrier();
    __builtin_amdgcn_sched_barrier(0);
    COMPUTE((NT - 1) % 3);

#pragma unroll
    for (int i = 0; i < 4; ++i)
#pragma unroll
        for (int j = 0; j < NJ; ++j)
#pragma unroll
            for (int r = 0; r < 4; ++r) {
                int row = m0 + wm + i * 16 + ((lane >> 4) << 2) + r;
                int col = n0 + wn + j * 16 + (lane & 15);
                size_t idx = (size_t)row * N + col;
                float v = acc[i][j][r];
                if constexpr (EPI == 1) {
                    outf[idx] = v;
                } else if constexpr (EPI == 3) {
                    outf[idx] = e1[idx] + v;
                } else if constexpr (EPI == 4) {
                    float gg = e1[idx];
                    float sil = gg / (1.0f + __expf(-gg));
                    outb[idx] = (bf16)(sil * v);
                } else if constexpr (EPI == 5) {
                    if (col >= 3 * DIM) {
                        float g = 1.0f / (1.0f + __expf(-(v + bias[col - 3 * DIM])));
                        outb[idx] = (bf16)g;
                    } else {
                        outb[idx] = (bf16)v;
                    }
                }
            }
}

extern "C" void kernel_launch(void* const* d_in, const int* in_sizes, int n_in,
                              void* d_out, int out_size, void* d_ws, size_t ws_size,
                              hipStream_t stream)
{
    const float* x        = (const float*)d_in[0];
    const float* n1s      = (const float*)d_in[1];
    const float* n2s      = (const float*)d_in[2];
    const float* w_qkv    = (const float*)d_in[3];
    const float* w_out    = (const float*)d_in[4];
    const float* w_gate   = (const float*)d_in[5];
    const float* b_gate   = (const float*)d_in[6];
    const float* pos_bias = (const float*)d_in[7];
    const float* w_ffng   = (const float*)d_in[8];
    const float* w_ffnu   = (const float*)d_in[9];
    const float* w_ffnd   = (const float*)d_in[10];
    const int* offsets    = (const int*)d_in[11];
    const int O = in_sizes[11];
    float* out = (float*)d_out;

    char* ws = (char*)d_ws;
    size_t cur = 0;
    auto alloc = [&](size_t bytes) -> void* {
        void* p = ws + cur;
        cur += (bytes + 255) & ~(size_t)255;
        return p;
    };
    bf16*  xnb    = (bf16*)alloc((size_t)N_TOK * DIM * 2);
    bf16*  qkvgb  = (bf16*)alloc((size_t)N_TOK * 4 * DIM * 2);
    bf16*  attgb  = (bf16*)alloc((size_t)N_TOK * DIM * 2);
    float* x1     = (float*)alloc((size_t)N_TOK * DIM * 4);
    bf16*  xn2b   = (bf16*)alloc((size_t)N_TOK * DIM * 2);
    float* hg     = (float*)alloc((size_t)N_TOK * FFN_DIM * 4);
    bf16*  hb     = (bf16*)alloc((size_t)N_TOK * FFN_DIM * 2);
    bf16*  wqkvgT = (bf16*)alloc((size_t)4 * DIM * DIM * 2);
    bf16*  woutT  = (bf16*)alloc((size_t)DIM * DIM * 2);
    bf16*  wffngT = (bf16*)alloc((size_t)DIM * FFN_DIM * 2);
    bf16*  wffnuT = (bf16*)alloc((size_t)DIM * FFN_DIM * 2);
    bf16*  wffndT = (bf16*)alloc((size_t)FFN_DIM * DIM * 2);

    dim3 tb(32, 8);
    transpose_cvt_kernel<<<dim3(3 * DIM / 32, DIM / 32), tb, 0, stream>>>(w_qkv, wqkvgT, DIM, 3 * DIM);
    transpose_cvt_kernel<<<dim3(DIM / 32, DIM / 32), tb, 0, stream>>>(w_gate, wqkvgT + (size_t)3 * DIM * DIM, DIM, DIM);
    transpose_cvt_kernel<<<dim3(DIM / 32, DIM / 32), tb, 0, stream>>>(w_out, woutT, DIM, DIM);
    transpose_cvt_kernel<<<dim3(FFN_DIM / 32, DIM / 32), tb, 0, stream>>>(w_ffng, wffngT, DIM, FFN_DIM);
    transpose_cvt_kernel<<<dim3(FFN_DIM / 32, DIM / 32), tb, 0, stream>>>(w_ffnu, wffnuT, DIM, FFN_DIM);
    transpose_cvt_kernel<<<dim3(DIM / 32, FFN_DIM / 32), tb, 0, stream>>>(w_ffnd, wffndT, FFN_DIM, DIM);

    rmsnorm_kernel<<<N_TOK, 256, 0, stream>>>(x, n1s, xnb);
    // fused qkv + gate GEMM: N = 4096
    gemm_kernel<128, 5><<<dim3(4 * DIM / 128, N_TOK / 128), 256, 0, stream>>>(
        xnb, wqkvgT, N_TOK, 4 * DIM, DIM, nullptr, qkvgb, nullptr, b_gate);
    attn_kernel<<<dim3(N_TOK), 256, 0, stream>>>(qkvgb, offsets, pos_bias, attgb, O);
    // x1 = x + attg @ w_out
    gemm_kernel<64, 3><<<dim3(DIM / 64, N_TOK / 128), 256, 0, stream>>>(
        attgb, woutT, N_TOK, DIM, DIM, x1, nullptr, x, nullptr);
    rmsnorm_kernel<<<N_TOK, 256, 0, stream>>>(x1, n2s, xn2b);
    // hg = xn2 @ w_ffn_gate (f32)
    gemm_kernel<128, 1><<<dim3(FFN_DIM / 128, N_TOK / 128), 256, 0, stream>>>(
        xn2b, wffngT, N_TOK, FFN_DIM, DIM, hg, nullptr, nullptr, nullptr);
    // hb = silu(hg) * (xn2 @ w_ffn_up)
    gemm_kernel<128, 4><<<dim3(FFN_DIM / 128, N_TOK / 128), 256, 0, stream>>>(
        xn2b, wffnuT, N_TOK, FFN_DIM, DIM, nullptr, hb, hg, nullptr);
    // out = x1 + hb @ w_ffn_down
    gemm_kernel<64, 3><<<dim3(DIM / 64, N_TOK / 128), 256, 0, stream>>>(
        hb, wffndT, N_TOK, DIM, FFN_DIM, out, nullptr, x1, nullptr);
}

// Round 4
// 163.534 us; speedup vs baseline: 2.1213x; 1.3521x over previous
//
#include <hip/hip_runtime.h>
#include <hip/hip_bf16.h>
#include <math.h>

typedef __bf16 bf16;
typedef __bf16 v8bf __attribute__((ext_vector_type(8)));
typedef __bf16 v4bf __attribute__((ext_vector_type(4)));
typedef float v4f __attribute__((ext_vector_type(4)));

#define N_TOK 2048
#define DIM 1024
#define NH 16
#define FFN_DIM 2816

#define GLL(g, l) __builtin_amdgcn_global_load_lds(                         \
    (const __attribute__((address_space(1))) uint32_t*)(g),                 \
    (__attribute__((address_space(3))) uint32_t*)(l), 16, 0, 0)

// ---------- all weight transposes+cvt in ONE launch ----------
// qkv:3072 tiles | gate:1024 | wout:1024 | ffng:2816 | ffnu:2816 | ffnd:2816
__global__ __launch_bounds__(256) void transpose_all_kernel(
    const float* __restrict__ w_qkv, const float* __restrict__ w_gate,
    const float* __restrict__ w_out, const float* __restrict__ w_ffng,
    const float* __restrict__ w_ffnu, const float* __restrict__ w_ffnd,
    bf16* __restrict__ wqkvgT, bf16* __restrict__ woutT,
    bf16* __restrict__ wcatT, bf16* __restrict__ wffndT)
{
    int bid = blockIdx.x;
    const float* W; bf16* D; int Kd, Nc, nb, kb, dstbase;
    if (bid < 3072) {
        W = w_qkv; D = wqkvgT; Kd = 1024; Nc = 3072;
        nb = (bid % 96) * 32; kb = (bid / 96) * 32; dstbase = nb;
    } else if (bid < 4096) { int b = bid - 3072;
        W = w_gate; D = wqkvgT; Kd = 1024; Nc = 1024;
        nb = (b % 32) * 32; kb = (b / 32) * 32; dstbase = 3072 + nb;
    } else if (bid < 5120) { int b = bid - 4096;
        W = w_out; D = woutT; Kd = 1024; Nc = 1024;
        nb = (b % 32) * 32; kb = (b / 32) * 32; dstbase = nb;
    } else if (bid < 7936) { int b = bid - 5120;
        W = w_ffng; D = wcatT; Kd = 1024; Nc = 2816;
        nb = (b % 88) * 32; kb = (b / 88) * 32;
        dstbase = (nb >> 6) * 128 + (nb & 63);
    } else if (bid < 10752) { int b = bid - 7936;
        W = w_ffnu; D = wcatT; Kd = 1024; Nc = 2816;
        nb = (b % 88) * 32; kb = (b / 88) * 32;
        dstbase = (nb >> 6) * 128 + 64 + (nb & 63);
    } else { int b = bid - 10752;
        W = w_ffnd; D = wffndT; Kd = 2816; Nc = 1024;
        nb = (b % 32) * 32; kb = (b / 32) * 32; dstbase = nb;
    }
    __shared__ float tile[32][33];
    int tx = threadIdx.x, ty = threadIdx.y;
#pragma unroll
    for (int r = 0; r < 4; ++r)
        tile[ty + r * 8][tx] = W[(size_t)(kb + ty + r * 8) * Nc + nb + tx];
    __syncthreads();
#pragma unroll
    for (int r = 0; r < 4; ++r)
        D[(size_t)(dstbase + ty + r * 8) * Kd + kb + tx] = (bf16)tile[tx][ty + r * 8];
}

// ---------- RMSNorm (f32 in -> bf16 out) ----------
__global__ __launch_bounds__(256) void rmsnorm_kernel(
    const float* __restrict__ x, const float* __restrict__ scale, bf16* __restrict__ out)
{
    int row = blockIdx.x, tid = threadIdx.x;
    float4 v = ((const float4*)(x + (size_t)row * DIM))[tid];
    float ss = v.x * v.x + v.y * v.y + v.z * v.z + v.w * v.w;
#pragma unroll
    for (int off = 32; off > 0; off >>= 1) ss += __shfl_down(ss, off);
    __shared__ float ps[4];
    if ((tid & 63) == 0) ps[tid >> 6] = ss;
    __syncthreads();
    float tot = ps[0] + ps[1] + ps[2] + ps[3];
    float inv = rsqrtf(tot * (1.0f / DIM) + 1e-6f);
    float4 s = ((const float4*)scale)[tid];
    union { bf16 b[4]; uint2 u; } p;
    p.b[0] = (bf16)(v.x * inv * s.x);
    p.b[1] = (bf16)(v.y * inv * s.y);
    p.b[2] = (bf16)(v.z * inv * s.z);
    p.b[3] = (bf16)(v.w * inv * s.w);
    ((uint2*)(out + (size_t)row * DIM))[tid] = p.u;
}

// ---------- gathered-offset attention + gate multiply ----------
__global__ __launch_bounds__(256) void attn_kernel(
    const bf16* __restrict__ qkvg, const int* __restrict__ offs,
    const float* __restrict__ pos_bias, bf16* __restrict__ attgb, int Ounused)
{
    constexpr int O = 44;
    const int t = blockIdx.x, tid = threadIdx.x;
    const int h = tid >> 4, j16 = tid & 15;
    const size_t RS = 4 * DIM;
    __shared__ float sS[O][16];
    __shared__ float sPB[O * 16];
    __shared__ int so[O];
    if (tid < O) so[tid] = offs[tid];
    for (int i = tid; i < O * 16; i += 256) sPB[i] = pos_bias[i];
    __syncthreads();

    v4bf qv = *(const v4bf*)(qkvg + (size_t)t * RS + tid * 4);
    float q0 = (float)qv[0] * 0.125f, q1 = (float)qv[1] * 0.125f;
    float q2 = (float)qv[2] * 0.125f, q3 = (float)qv[3] * 0.125f;

#pragma unroll 4
    for (int o = 0; o < O; ++o) {
        int src = t - so[o];
        int srcc = src < 0 ? 0 : src;
        v4bf kv = *(const v4bf*)(qkvg + (size_t)srcc * RS + DIM + tid * 4);
        float p = q0 * (float)kv[0] + q1 * (float)kv[1]
                + q2 * (float)kv[2] + q3 * (float)kv[3];
        p += __shfl_xor(p, 1);
        p += __shfl_xor(p, 2);
        p += __shfl_xor(p, 4);
        p += __shfl_xor(p, 8);
        float s = (src >= 0) ? p + sPB[o * NH + h] : -INFINITY;
        if (j16 == 0) sS[o][h] = s;
    }
    __syncthreads();

    float mx = -INFINITY;
#pragma unroll
    for (int o = j16; o < O; o += 16) mx = fmaxf(mx, sS[o][h]);
    mx = fmaxf(mx, __shfl_xor(mx, 1));
    mx = fmaxf(mx, __shfl_xor(mx, 2));
    mx = fmaxf(mx, __shfl_xor(mx, 4));
    mx = fmaxf(mx, __shfl_xor(mx, 8));
    float sum = 0.f;
#pragma unroll
    for (int o = j16; o < O; o += 16) {
        float e = __expf(sS[o][h] - mx);
        sS[o][h] = e;
        sum += e;
    }
    sum += __shfl_xor(sum, 1);
    sum += __shfl_xor(sum, 2);
    sum += __shfl_xor(sum, 4);
    sum += __shfl_xor(sum, 8);
    float inv = 1.0f / sum;
    __syncthreads();

    float a0 = 0.f, a1 = 0.f, a2 = 0.f, a3 = 0.f;
#pragma unroll 4
    for (int o = 0; o < O; ++o) {
        int src = t - so[o];
        int srcc = src < 0 ? 0 : src;
        float a = sS[o][h];                 // 0 for invalid offsets
        v4bf vv = *(const v4bf*)(qkvg + (size_t)srcc * RS + 2 * DIM + tid * 4);
        a0 += a * (float)vv[0];
        a1 += a * (float)vv[1];
        a2 += a * (float)vv[2];
        a3 += a * (float)vv[3];
    }
    v4bf gv = *(const v4bf*)(qkvg + (size_t)t * RS + 3 * DIM + tid * 4);
    v4bf ov;
    ov[0] = (bf16)(a0 * inv * (float)gv[0]);
    ov[1] = (bf16)(a1 * inv * (float)gv[1]);
    ov[2] = (bf16)(a2 * inv * (float)gv[2]);
    ov[3] = (bf16)(a3 * inv * (float)gv[3]);
    *(v4bf*)(attgb + (size_t)t * DIM + tid * 4) = ov;
}

// ---------- bf16 MFMA GEMM, NBUF=2, counted vmcnt, XOR-swizzled LDS ----------
// EPI: 3 = residual f32 (outf = e1 + acc)
//      5 = qkv+gate (col<3072: bf16 acc; else bf16 sigmoid(acc+bias[col-3072]))
//      6 = interleaved ffn gate/up: outb[.,n0/2+c] = silu(gate) * up  via LDS exchange
template<int BM, int BN, int NTHR, int EPI>
__global__ __launch_bounds__(NTHR) void gemm_kernel(
    const bf16* __restrict__ A, const bf16* __restrict__ Bt,
    int M, int N, int K,
    float* __restrict__ outf, bf16* __restrict__ outb,
    const float* __restrict__ e1, const float* __restrict__ bias)
{
    constexpr int WAVES = NTHR / 64;
    constexpr int WCOLS = WAVES / 2;
    constexpr int WME = BM / 2;         // per-wave M extent
    constexpr int WNE = BN / WCOLS;     // per-wave N extent
    constexpr int MI = WME / 16;
    constexpr int NJ = WNE / 16;
    constexpr int STAGE_BYTES = 2 * (BM + BN) * 32 * 2;
    constexpr int EPI_BYTES = (EPI == 6) ? BM * 66 * 4 : 0;
    constexpr int SMEM_BYTES = STAGE_BYTES > EPI_BYTES ? STAGE_BYTES : EPI_BYTES;
    __shared__ __align__(16) char smem[SMEM_BYTES];
    bf16* AsB = (bf16*)smem;                          // [2][BM*32]
    bf16* BsB = (bf16*)(smem + 2 * BM * 32 * 2);      // [2][BN*32]

    const int tid = threadIdx.x;
    const int m0 = blockIdx.y * BM, n0 = blockIdx.x * BN;
    const int lane = tid & 63, wave = tid >> 6;
    const int wr = wave / WCOLS, wc = wave % WCOLS;
    const int wm = wr * WME, wn = wc * WNE;
    const int lrow = lane & 15, l16 = lane >> 4;

    // staging: thread -> 16B chunk (srow, tid&3); LDS linear (lane*16 per wave),
    // global 16B-column pre-swizzled by (row>>1)&3
    const int srow = tid >> 2;
    const int gcol = ((tid & 3) ^ ((srow >> 1) & 3)) * 8;
    const int lofs = srow * 32 + (tid & 3) * 8;
    const bf16* gA = A + (size_t)(m0 + srow) * K + gcol;
    const bf16* gB = Bt + (size_t)(n0 + srow) * K + gcol;

    auto STAGE = [&](int b, int kt) {
        const int ko = kt * 32;
        GLL(gA + ko, AsB + b * BM * 32 + lofs);
        GLL(gB + ko, BsB + b * BN * 32 + lofs);
    };

    v4f acc[MI][NJ] = {};
    auto COMPUTE = [&](int b) {
        v8bf af[MI], bfr[NJ];
#pragma unroll
        for (int i = 0; i < MI; ++i) {
            int r = wm + i * 16 + lrow;
            af[i] = *(v8bf*)&AsB[b * BM * 32 + r * 32 + ((l16 ^ ((r >> 1) & 3)) * 8)];
        }
#pragma unroll
        for (int j = 0; j < NJ; ++j) {
            int r = wn + j * 16 + lrow;
            bfr[j] = *(v8bf*)&BsB[b * BN * 32 + r * 32 + ((l16 ^ ((r >> 1) & 3)) * 8)];
        }
        __builtin_amdgcn_s_setprio(1);
#pragma unroll
        for (int i = 0; i < MI; ++i)
#pragma unroll
            for (int j = 0; j < NJ; ++j)
                acc[i][j] = __builtin_amdgcn_mfma_f32_16x16x32_bf16(af[i], bfr[j], acc[i][j], 0, 0, 0);
        __builtin_amdgcn_s_setprio(0);
    };

    const int NT = K >> 5;
    STAGE(0, 0); STAGE(1, 1);
    for (int t = 0; t < NT; ++t) {
        if (t < NT - 1) asm volatile("s_waitcnt vmcnt(2)" ::: "memory");
        else            asm volatile("s_waitcnt vmcnt(0)" ::: "memory");
        __builtin_amdgcn_s_barrier();
        __builtin_amdgcn_sched_barrier(0);
        COMPUTE(t & 1);
        __builtin_amdgcn_sched_barrier(0);
        __builtin_amdgcn_s_barrier();
        if (t + 2 < NT) STAGE(t & 1, t + 2);
    }

    if constexpr (EPI == 6) {
        float* eps = (float*)smem;
        const bool isGate = (wn < 64);
        if (isGate) {
#pragma unroll
            for (int i = 0; i < MI; ++i)
#pragma unroll
                for (int j = 0; j < NJ; ++j)
#pragma unroll
                    for (int r = 0; r < 4; ++r) {
                        int rowL = wm + i * 16 + l16 * 4 + r;
                        int colL = wn + j * 16 + lrow;
                        eps[rowL * 66 + colL] = acc[i][j][r];
                    }
        }
        __builtin_amdgcn_s_barrier();
        if (!isGate) {
            const int halfN = N >> 1;
#pragma unroll
            for (int i = 0; i < MI; ++i)
#pragma unroll
                for (int j = 0; j < NJ; ++j)
#pragma unroll
                    for (int r = 0; r < 4; ++r) {
                        int rowL = wm + i * 16 + l16 * 4 + r;
                        int colU = wn - 64 + j * 16 + lrow;
                        float g = eps[rowL * 66 + colU];
                        float sil = g / (1.0f + __expf(-g));
                        float u = acc[i][j][r];
                        outb[(size_t)(m0 + rowL) * halfN + (n0 >> 1) + colU] = (bf16)(sil * u);
                    }
        }
        return;
    }

#pragma unroll
    for (int i = 0; i < MI; ++i)
#pragma unroll
        for (int j = 0; j < NJ; ++j)
#pragma unroll
            for (int r = 0; r < 4; ++r) {
                int row = m0 + wm + i * 16 + l16 * 4 + r;
                int col = n0 + wn + j * 16 + lrow;
                size_t idx = (size_t)row * N + col;
                float v = acc[i][j][r];
                if constexpr (EPI == 3) {
                    outf[idx] = e1[idx] + v;
                } else if constexpr (EPI == 5) {
                    if (col >= 3 * DIM) {
                        float g = 1.0f / (1.0f + __expf(-(v + bias[col - 3 * DIM])));
                        outb[idx] = (bf16)g;
                    } else {
                        outb[idx] = (bf16)v;
                    }
                }
            }
}

extern "C" void kernel_launch(void* const* d_in, const int* in_sizes, int n_in,
                              void* d_out, int out_size, void* d_ws, size_t ws_size,
                              hipStream_t stream)
{
    const float* x        = (const float*)d_in[0];
    const float* n1s      = (const float*)d_in[1];
    const float* n2s      = (const float*)d_in[2];
    const float* w_qkv    = (const float*)d_in[3];
    const float* w_out    = (const float*)d_in[4];
    const float* w_gate   = (const float*)d_in[5];
    const float* b_gate   = (const float*)d_in[6];
    const float* pos_bias = (const float*)d_in[7];
    const float* w_ffng   = (const float*)d_in[8];
    const float* w_ffnu   = (const float*)d_in[9];
    const float* w_ffnd   = (const float*)d_in[10];
    const int* offsets    = (const int*)d_in[11];
    const int O = in_sizes[11];
    float* out = (float*)d_out;

    char* ws = (char*)d_ws;
    size_t cur = 0;
    auto alloc = [&](size_t bytes) -> void* {
        void* p = ws + cur;
        cur += (bytes + 255) & ~(size_t)255;
        return p;
    };
    bf16*  xnb    = (bf16*)alloc((size_t)N_TOK * DIM * 2);
    bf16*  qkvgb  = (bf16*)alloc((size_t)N_TOK * 4 * DIM * 2);
    bf16*  attgb  = (bf16*)alloc((size_t)N_TOK * DIM * 2);
    float* x1     = (float*)alloc((size_t)N_TOK * DIM * 4);
    bf16*  xn2b   = (bf16*)alloc((size_t)N_TOK * DIM * 2);
    bf16*  hb     = (bf16*)alloc((size_t)N_TOK * FFN_DIM * 2);
    bf16*  wqkvgT = (bf16*)alloc((size_t)4 * DIM * DIM * 2);
    bf16*  woutT  = (bf16*)alloc((size_t)DIM * DIM * 2);
    bf16*  wcatT  = (bf16*)alloc((size_t)2 * FFN_DIM * DIM * 2);
    bf16*  wffndT = (bf16*)alloc((size_t)FFN_DIM * DIM * 2);

    transpose_all_kernel<<<13568, dim3(32, 8), 0, stream>>>(
        w_qkv, w_gate, w_out, w_ffng, w_ffnu, w_ffnd,
        wqkvgT, woutT, wcatT, wffndT);

    rmsnorm_kernel<<<N_TOK, 256, 0, stream>>>(x, n1s, xnb);
    // fused qkv + gate: N = 4096, 8-wave 128x128
    gemm_kernel<128, 128, 512, 5><<<dim3(32, 16), 512, 0, stream>>>(
        xnb, wqkvgT, N_TOK, 4 * DIM, DIM, nullptr, qkvgb, nullptr, b_gate);
    attn_kernel<<<dim3(N_TOK), 256, 0, stream>>>(qkvgb, offsets, pos_bias, attgb, O);
    // x1 = x + attg @ w_out  (64x64 tiles, grid 512)
    gemm_kernel<64, 64, 256, 3><<<dim3(16, 32), 256, 0, stream>>>(
        attgb, woutT, N_TOK, DIM, DIM, x1, nullptr, x, nullptr);
    rmsnorm_kernel<<<N_TOK, 256, 0, stream>>>(x1, n2s, xn2b);
    // fused ffn gate|up interleaved: N = 5632, silu fused via LDS exchange
    gemm_kernel<128, 128, 512, 6><<<dim3(44, 16), 512, 0, stream>>>(
        xn2b, wcatT, N_TOK, 2 * FFN_DIM, DIM, nullptr, hb, nullptr, nullptr);
    // out = x1 + hb @ w_ffn_down  (64x64 tiles, grid 512)
    gemm_kernel<64, 64, 256, 3><<<dim3(16, 32), 256, 0, stream>>>(
        hb, wffndT, N_TOK, DIM, FFN_DIM, out, nullptr, x1, nullptr);
}

// Round 5
// 150.955 us; speedup vs baseline: 2.2980x; 1.0833x over previous
//
#include <hip/hip_runtime.h>
#include <hip/hip_bf16.h>
#include <math.h>

typedef __bf16 bf16;
typedef __bf16 v8bf __attribute__((ext_vector_type(8)));
typedef __bf16 v4bf __attribute__((ext_vector_type(4)));
typedef float v4f __attribute__((ext_vector_type(4)));

#define N_TOK 2048
#define DIM 1024
#define NH 16
#define FFN_DIM 2816

#define GLL(g, l) __builtin_amdgcn_global_load_lds(                         \
    (const __attribute__((address_space(1))) uint32_t*)(g),                 \
    (__attribute__((address_space(3))) uint32_t*)(l), 16, 0, 0)

// ---------- all weight transposes+cvt in ONE launch ----------
__global__ __launch_bounds__(256) void transpose_all_kernel(
    const float* __restrict__ w_qkv, const float* __restrict__ w_gate,
    const float* __restrict__ w_out, const float* __restrict__ w_ffng,
    const float* __restrict__ w_ffnu, const float* __restrict__ w_ffnd,
    bf16* __restrict__ wqkvgT, bf16* __restrict__ woutT,
    bf16* __restrict__ wcatT, bf16* __restrict__ wffndT)
{
    int bid = blockIdx.x;
    const float* W; bf16* D; int Kd, Nc, nb, kb, dstbase;
    if (bid < 3072) {
        W = w_qkv; D = wqkvgT; Kd = 1024; Nc = 3072;
        nb = (bid % 96) * 32; kb = (bid / 96) * 32; dstbase = nb;
    } else if (bid < 4096) { int b = bid - 3072;
        W = w_gate; D = wqkvgT; Kd = 1024; Nc = 1024;
        nb = (b % 32) * 32; kb = (b / 32) * 32; dstbase = 3072 + nb;
    } else if (bid < 5120) { int b = bid - 4096;
        W = w_out; D = woutT; Kd = 1024; Nc = 1024;
        nb = (b % 32) * 32; kb = (b / 32) * 32; dstbase = nb;
    } else if (bid < 7936) { int b = bid - 5120;
        W = w_ffng; D = wcatT; Kd = 1024; Nc = 2816;
        nb = (b % 88) * 32; kb = (b / 88) * 32;
        dstbase = (nb >> 6) * 128 + (nb & 63);
    } else if (bid < 10752) { int b = bid - 7936;
        W = w_ffnu; D = wcatT; Kd = 1024; Nc = 2816;
        nb = (b % 88) * 32; kb = (b / 88) * 32;
        dstbase = (nb >> 6) * 128 + 64 + (nb & 63);
    } else { int b = bid - 10752;
        W = w_ffnd; D = wffndT; Kd = 2816; Nc = 1024;
        nb = (b % 32) * 32; kb = (b / 32) * 32; dstbase = nb;
    }
    __shared__ float tile[32][33];
    int tx = threadIdx.x, ty = threadIdx.y;
#pragma unroll
    for (int r = 0; r < 4; ++r)
        tile[ty + r * 8][tx] = W[(size_t)(kb + ty + r * 8) * Nc + nb + tx];
    __syncthreads();
#pragma unroll
    for (int r = 0; r < 4; ++r)
        D[(size_t)(dstbase + ty + r * 8) * Kd + kb + tx] = (bf16)tile[tx][ty + r * 8];
}

// ---------- RMSNorm (f32 in -> bf16 out) ----------
__global__ __launch_bounds__(256) void rmsnorm_kernel(
    const float* __restrict__ x, const float* __restrict__ scale, bf16* __restrict__ out)
{
    int row = blockIdx.x, tid = threadIdx.x;
    float4 v = ((const float4*)(x + (size_t)row * DIM))[tid];
    float ss = v.x * v.x + v.y * v.y + v.z * v.z + v.w * v.w;
#pragma unroll
    for (int off = 32; off > 0; off >>= 1) ss += __shfl_down(ss, off);
    __shared__ float ps[4];
    if ((tid & 63) == 0) ps[tid >> 6] = ss;
    __syncthreads();
    float tot = ps[0] + ps[1] + ps[2] + ps[3];
    float inv = rsqrtf(tot * (1.0f / DIM) + 1e-6f);
    float4 s = ((const float4*)scale)[tid];
    union { bf16 b[4]; uint2 u; } p;
    p.b[0] = (bf16)(v.x * inv * s.x);
    p.b[1] = (bf16)(v.y * inv * s.y);
    p.b[2] = (bf16)(v.z * inv * s.z);
    p.b[3] = (bf16)(v.w * inv * s.w);
    ((uint2*)(out + (size_t)row * DIM))[tid] = p.u;
}

// ---------- gathered-offset attention + gate multiply ----------
// phase 1: 4-lane group per (offset, head): lane owns 16 dims, 2-shfl reduce.
// phase 2: 16 lanes per head softmax. phase 3: thread owns 4 dims of one head.
__global__ __launch_bounds__(256) void attn_kernel(
    const bf16* __restrict__ qkvg, const int* __restrict__ offs,
    const float* __restrict__ pos_bias, bf16* __restrict__ attgb)
{
    constexpr int O = 44;
    const int t = blockIdx.x, tid = threadIdx.x;
    const int wv = tid >> 6, lane = tid & 63;
    const int h1 = lane >> 2, l4 = lane & 3;
    const size_t RS = 4 * DIM;
    __shared__ float sS[O][17];
    __shared__ float sPB[O * 16];
    __shared__ int so[O];
    if (tid < O) so[tid] = offs[tid];
    for (int i = tid; i < O * 16; i += 256) sPB[i] = pos_bias[i];
    __syncthreads();

    // Q slice: chunks l4 and l4+4 (8 bf16 each) of head h1, pre-scaled
    const bf16* qbase = qkvg + (size_t)t * RS + h1 * 64;
    v8bf q0v = *(const v8bf*)(qbase + l4 * 8);
    v8bf q1v = *(const v8bf*)(qbase + 32 + l4 * 8);
    float qa[16];
#pragma unroll
    for (int e = 0; e < 8; ++e) {
        qa[e] = (float)q0v[e] * 0.125f;
        qa[8 + e] = (float)q1v[e] * 0.125f;
    }

#pragma unroll 4
    for (int it = 0; it < 11; ++it) {
        const int o = it * 4 + wv;
        const int src = t - so[o];
        const int srcc = src < 0 ? 0 : src;
        const bf16* kbase = qkvg + (size_t)srcc * RS + DIM + h1 * 64;
        v8bf k0 = *(const v8bf*)(kbase + l4 * 8);
        v8bf k1 = *(const v8bf*)(kbase + 32 + l4 * 8);
        float p = 0.f;
#pragma unroll
        for (int e = 0; e < 8; ++e)
            p += qa[e] * (float)k0[e];
#pragma unroll
        for (int e = 0; e < 8; ++e)
            p += qa[8 + e] * (float)k1[e];
        p += __shfl_xor(p, 1);
        p += __shfl_xor(p, 2);
        float s = (src >= 0) ? p + sPB[o * NH + h1] : -INFINITY;
        if (l4 == 0) sS[o][h1] = s;
    }
    __syncthreads();

    // phase 2: per-head softmax stats
    const int h = tid >> 4, j16 = tid & 15;
    float mx = -INFINITY;
#pragma unroll
    for (int o = j16; o < O; o += 16) mx = fmaxf(mx, sS[o][h]);
    mx = fmaxf(mx, __shfl_xor(mx, 1));
    mx = fmaxf(mx, __shfl_xor(mx, 2));
    mx = fmaxf(mx, __shfl_xor(mx, 4));
    mx = fmaxf(mx, __shfl_xor(mx, 8));
    float sum = 0.f;
#pragma unroll
    for (int o = j16; o < O; o += 16) {
        float e = __expf(sS[o][h] - mx);
        sS[o][h] = e;
        sum += e;
    }
    sum += __shfl_xor(sum, 1);
    sum += __shfl_xor(sum, 2);
    sum += __shfl_xor(sum, 4);
    sum += __shfl_xor(sum, 8);
    float inv = 1.0f / sum;
    __syncthreads();

    // phase 3: PV accumulate (alpha=0 for invalid offsets)
    float a0 = 0.f, a1 = 0.f, a2 = 0.f, a3 = 0.f;
#pragma unroll 4
    for (int o = 0; o < O; ++o) {
        int src = t - so[o];
        int srcc = src < 0 ? 0 : src;
        float a = sS[o][h];
        v4bf vv = *(const v4bf*)(qkvg + (size_t)srcc * RS + 2 * DIM + tid * 4);
        a0 += a * (float)vv[0];
        a1 += a * (float)vv[1];
        a2 += a * (float)vv[2];
        a3 += a * (float)vv[3];
    }
    v4bf gv = *(const v4bf*)(qkvg + (size_t)t * RS + 3 * DIM + tid * 4);
    v4bf ov;
    ov[0] = (bf16)(a0 * inv * (float)gv[0]);
    ov[1] = (bf16)(a1 * inv * (float)gv[1]);
    ov[2] = (bf16)(a2 * inv * (float)gv[2]);
    ov[3] = (bf16)(a3 * inv * (float)gv[3]);
    *(v4bf*)(attgb + (size_t)t * DIM + tid * 4) = ov;
}

// ---------- bf16 MFMA GEMM, NBUF=2, counted vmcnt, XOR-swizzled LDS ----------
// EPI: 3 = residual f32 (outf = e1 + acc)
//      5 = qkv+gate (col<3072: bf16 acc; else bf16 sigmoid(acc+bias[col-3072]))
//      6 = interleaved ffn gate/up: outb[.,n0/2+c] = silu(gate) * up  via LDS exchange
template<int BM, int BN, int NTHR, int EPI>
__global__ __launch_bounds__(NTHR) void gemm_kernel(
    const bf16* __restrict__ A, const bf16* __restrict__ Bt,
    int M, int N, int K,
    float* __restrict__ outf, bf16* __restrict__ outb,
    const float* __restrict__ e1, const float* __restrict__ bias)
{
    constexpr int WAVES = NTHR / 64;
    constexpr int WCOLS = WAVES / 2;
    constexpr int WME = BM / 2;
    constexpr int WNE = BN / WCOLS;
    constexpr int MI = WME / 16;
    constexpr int NJ = WNE / 16;
    constexpr int STAGE_BYTES = 2 * (BM + BN) * 32 * 2;
    constexpr int EPI_BYTES = (EPI == 6) ? BM * 66 * 4 : 0;
    constexpr int SMEM_BYTES = STAGE_BYTES > EPI_BYTES ? STAGE_BYTES : EPI_BYTES;
    __shared__ __align__(16) char smem[SMEM_BYTES];
    bf16* AsB = (bf16*)smem;
    bf16* BsB = (bf16*)(smem + 2 * BM * 32 * 2);

    const int tid = threadIdx.x;
    const int m0 = blockIdx.y * BM, n0 = blockIdx.x * BN;
    const int lane = tid & 63, wave = tid >> 6;
    const int wr = wave / WCOLS, wc = wave % WCOLS;
    const int wm = wr * WME, wn = wc * WNE;
    const int lrow = lane & 15, l16 = lane >> 4;

    const int srow = tid >> 2;
    const int gcol = ((tid & 3) ^ ((srow >> 1) & 3)) * 8;
    const int lofs = srow * 32 + (tid & 3) * 8;
    const bf16* gA = A + (size_t)(m0 + srow) * K + gcol;
    const bf16* gB = Bt + (size_t)(n0 + srow) * K + gcol;

    auto STAGE = [&](int b, int kt) {
        const int ko = kt * 32;
        GLL(gA + ko, AsB + b * BM * 32 + lofs);
        GLL(gB + ko, BsB + b * BN * 32 + lofs);
    };

    v4f acc[MI][NJ] = {};
    auto COMPUTE = [&](int b) {
        v8bf af[MI], bfr[NJ];
#pragma unroll
        for (int i = 0; i < MI; ++i) {
            int r = wm + i * 16 + lrow;
            af[i] = *(v8bf*)&AsB[b * BM * 32 + r * 32 + ((l16 ^ ((r >> 1) & 3)) * 8)];
        }
#pragma unroll
        for (int j = 0; j < NJ; ++j) {
            int r = wn + j * 16 + lrow;
            bfr[j] = *(v8bf*)&BsB[b * BN * 32 + r * 32 + ((l16 ^ ((r >> 1) & 3)) * 8)];
        }
        __builtin_amdgcn_s_setprio(1);
#pragma unroll
        for (int i = 0; i < MI; ++i)
#pragma unroll
            for (int j = 0; j < NJ; ++j)
                acc[i][j] = __builtin_amdgcn_mfma_f32_16x16x32_bf16(af[i], bfr[j], acc[i][j], 0, 0, 0);
        __builtin_amdgcn_s_setprio(0);
    };

    const int NT = K >> 5;
    STAGE(0, 0); STAGE(1, 1);
    for (int t = 0; t < NT; ++t) {
        if (t < NT - 1) asm volatile("s_waitcnt vmcnt(2)" ::: "memory");
        else            asm volatile("s_waitcnt vmcnt(0)" ::: "memory");
        __builtin_amdgcn_s_barrier();
        __builtin_amdgcn_sched_barrier(0);
        COMPUTE(t & 1);
        __builtin_amdgcn_sched_barrier(0);
        __builtin_amdgcn_s_barrier();
        if (t + 2 < NT) STAGE(t & 1, t + 2);
    }

    if constexpr (EPI == 6) {
        float* eps = (float*)smem;
        const bool isGate = (wn < 64);
        if (isGate) {
#pragma unroll
            for (int i = 0; i < MI; ++i)
#pragma unroll
                for (int j = 0; j < NJ; ++j)
#pragma unroll
                    for (int r = 0; r < 4; ++r) {
                        int rowL = wm + i * 16 + l16 * 4 + r;
                        int colL = wn + j * 16 + lrow;
                        eps[rowL * 66 + colL] = acc[i][j][r];
                    }
        }
        __builtin_amdgcn_s_barrier();
        if (!isGate) {
            const int halfN = N >> 1;
#pragma unroll
            for (int i = 0; i < MI; ++i)
#pragma unroll
                for (int j = 0; j < NJ; ++j)
#pragma unroll
                    for (int r = 0; r < 4; ++r) {
                        int rowL = wm + i * 16 + l16 * 4 + r;
                        int colU = wn - 64 + j * 16 + lrow;
                        float g = eps[rowL * 66 + colU];
                        float sil = g / (1.0f + __expf(-g));
                        float u = acc[i][j][r];
                        outb[(size_t)(m0 + rowL) * halfN + (n0 >> 1) + colU] = (bf16)(sil * u);
                    }
        }
        return;
    }

#pragma unroll
    for (int i = 0; i < MI; ++i)
#pragma unroll
        for (int j = 0; j < NJ; ++j)
#pragma unroll
            for (int r = 0; r < 4; ++r) {
                int row = m0 + wm + i * 16 + l16 * 4 + r;
                int col = n0 + wn + j * 16 + lrow;
                size_t idx = (size_t)row * N + col;
                float v = acc[i][j][r];
                if constexpr (EPI == 3) {
                    outf[idx] = e1[idx] + v;
                } else if constexpr (EPI == 5) {
                    if (col >= 3 * DIM) {
                        float g = 1.0f / (1.0f + __expf(-(v + bias[col - 3 * DIM])));
                        outb[idx] = (bf16)g;
                    } else {
                        outb[idx] = (bf16)v;
                    }
                }
            }
}

extern "C" void kernel_launch(void* const* d_in, const int* in_sizes, int n_in,
                              void* d_out, int out_size, void* d_ws, size_t ws_size,
                              hipStream_t stream)
{
    const float* x        = (const float*)d_in[0];
    const float* n1s      = (const float*)d_in[1];
    const float* n2s      = (const float*)d_in[2];
    const float* w_qkv    = (const float*)d_in[3];
    const float* w_out    = (const float*)d_in[4];
    const float* w_gate   = (const float*)d_in[5];
    const float* b_gate   = (const float*)d_in[6];
    const float* pos_bias = (const float*)d_in[7];
    const float* w_ffng   = (const float*)d_in[8];
    const float* w_ffnu   = (const float*)d_in[9];
    const float* w_ffnd   = (const float*)d_in[10];
    const int* offsets    = (const int*)d_in[11];
    float* out = (float*)d_out;

    char* ws = (char*)d_ws;
    size_t cur = 0;
    auto alloc = [&](size_t bytes) -> void* {
        void* p = ws + cur;
        cur += (bytes + 255) & ~(size_t)255;
        return p;
    };
    bf16*  xnb    = (bf16*)alloc((size_t)N_TOK * DIM * 2);
    bf16*  qkvgb  = (bf16*)alloc((size_t)N_TOK * 4 * DIM * 2);
    bf16*  attgb  = (bf16*)alloc((size_t)N_TOK * DIM * 2);
    float* x1     = (float*)alloc((size_t)N_TOK * DIM * 4);
    bf16*  xn2b   = (bf16*)alloc((size_t)N_TOK * DIM * 2);
    bf16*  hb     = (bf16*)alloc((size_t)N_TOK * FFN_DIM * 2);
    bf16*  wqkvgT = (bf16*)alloc((size_t)4 * DIM * DIM * 2);
    bf16*  woutT  = (bf16*)alloc((size_t)DIM * DIM * 2);
    bf16*  wcatT  = (bf16*)alloc((size_t)2 * FFN_DIM * DIM * 2);
    bf16*  wffndT = (bf16*)alloc((size_t)FFN_DIM * DIM * 2);

    transpose_all_kernel<<<13568, dim3(32, 8), 0, stream>>>(
        w_qkv, w_gate, w_out, w_ffng, w_ffnu, w_ffnd,
        wqkvgT, woutT, wcatT, wffndT);

    rmsnorm_kernel<<<N_TOK, 256, 0, stream>>>(x, n1s, xnb);
    gemm_kernel<128, 128, 512, 5><<<dim3(32, 16), 512, 0, stream>>>(
        xnb, wqkvgT, N_TOK, 4 * DIM, DIM, nullptr, qkvgb, nullptr, b_gate);
    attn_kernel<<<dim3(N_TOK), 256, 0, stream>>>(qkvgb, offsets, pos_bias, attgb);
    gemm_kernel<64, 64, 256, 3><<<dim3(16, 32), 256, 0, stream>>>(
        attgb, woutT, N_TOK, DIM, DIM, x1, nullptr, x, nullptr);
    rmsnorm_kernel<<<N_TOK, 256, 0, stream>>>(x1, n2s, xn2b);
    gemm_kernel<128, 128, 512, 6><<<dim3(44, 16), 512, 0, stream>>>(
        xn2b, wcatT, N_TOK, 2 * FFN_DIM, DIM, nullptr, hb, nullptr, nullptr);
    gemm_kernel<64, 64, 256, 3><<<dim3(16, 32), 256, 0, stream>>>(
        hb, wffndT, N_TOK, DIM, FFN_DIM, out, nullptr, x1, nullptr);
}